// Round 3
// baseline (42099.948 us; speedup 1.0000x reference)
//
#include <hip/hip_runtime.h>

#define NROWS 65536
#define DD 512
#define MSZ (DD * DD)          // 262144 floats = 1 MB
#define NS_ITERS 7
#define BARY_ITERS 16
#define CSPLIT 16              // covsyrk split-K
#define CCHUNK (NROWS / CSPLIT)  // 4096

// ---------------- column means ----------------
__global__ __launch_bounds__(512) void colsum_kernel(const float* __restrict__ X,
                                                     const float* __restrict__ S,
                                                     float* __restrict__ sums) {
    const float* src = (blockIdx.y == 0) ? X : S;
    float* dst = sums + blockIdx.y * DD;
    int col = threadIdx.x;
    long base = (long)blockIdx.x * 256 * DD;
    float acc = 0.f;
    #pragma unroll 8
    for (int r = 0; r < 256; ++r)
        acc += src[base + (long)r * DD + col];
    atomicAdd(dst + col, acc);
}

__global__ __launch_bounds__(512) void finalize_mean_kernel(float* __restrict__ ws) {
    int t = threadIdx.x;
    const float inv_n = 1.f / (float)NROWS;
    float mc = ws[t] * inv_n;
    float ms = ws[DD + t] * inv_n;
    ws[t] = mc;
    ws[DD + t] = ms;
    ws[2 * DD + t] = 0.5f * (mc + ms);   // mu_bary
}

// ---------------- covariance: G = X^T X, 128x128 upper tiles, split-K atomics ----------------
__global__ __launch_bounds__(256) void covsyrk2_kernel(const float* __restrict__ X,
                                                       const float* __restrict__ S,
                                                       float* __restrict__ G) {
    int ta = blockIdx.x >> 2, tb = blockIdx.x & 3;
    if (ta > tb) return;                       // symmetry: upper 128-tiles only
    int a0 = ta << 7, b0 = tb << 7;
    const float* src = (blockIdx.z == 0) ? X : S;
    float* g = G + (long long)blockIdx.z * MSZ;
    long kbase = (long)blockIdx.y * CCHUNK;
    __shared__ float As[32][140];
    __shared__ float Bs[32][140];
    int t = threadIdx.x;
    int kr = t >> 5;              // 0..7
    int c4 = (t & 31) << 2;       // 0..124
    int sc = c4 + ((c4 >> 5) << 2);   // quad swizzle
    int iy = t >> 4, ix = t & 15;
    int aoff = (iy << 3) + ((iy >> 2) << 2);
    int boff = (ix << 3) + ((ix >> 2) << 2);
    float acc[8][8] = {};
    float4 pa[4], pb[4];
    #pragma unroll
    for (int p = 0; p < 4; ++p) {
        long row = (kbase + kr + p * 8) * DD;
        pa[p] = *(const float4*)(src + row + a0 + c4);
        pb[p] = *(const float4*)(src + row + b0 + c4);
    }
    for (int kb = 0; kb < CCHUNK; kb += 32) {
        __syncthreads();
        #pragma unroll
        for (int p = 0; p < 4; ++p) {
            *(float4*)&As[kr + p * 8][sc] = pa[p];
            *(float4*)&Bs[kr + p * 8][sc] = pb[p];
        }
        __syncthreads();
        if (kb + 32 < CCHUNK) {
            #pragma unroll
            for (int p = 0; p < 4; ++p) {
                long row = (kbase + kb + 32 + kr + p * 8) * DD;
                pa[p] = *(const float4*)(src + row + a0 + c4);
                pb[p] = *(const float4*)(src + row + b0 + c4);
            }
        }
        #pragma unroll 4
        for (int kk = 0; kk < 32; ++kk) {
            float a[8], bf[8];
            *(float4*)&a[0] = *(const float4*)&As[kk][aoff];
            *(float4*)&a[4] = *(const float4*)&As[kk][aoff + 4];
            *(float4*)&bf[0] = *(const float4*)&Bs[kk][boff];
            *(float4*)&bf[4] = *(const float4*)&Bs[kk][boff + 4];
            #pragma unroll
            for (int i = 0; i < 8; ++i)
                #pragma unroll
                for (int j = 0; j < 8; ++j)
                    acc[i][j] += a[i] * bf[j];
        }
    }
    #pragma unroll
    for (int i = 0; i < 8; ++i)
        #pragma unroll
        for (int j = 0; j < 8; ++j)
            atomicAdd(&g[(long)(a0 + (iy << 3) + i) * DD + b0 + (ix << 3) + j], acc[i][j]);
}

// cov = (G - n m m^T)/(n-1); mirror-read upper 128-tile; fused tr(covc) atomic into tr0
__global__ __launch_bounds__(512) void covfix_kernel(const float* __restrict__ Gt,
                                                     float* __restrict__ C,
                                                     const float* __restrict__ means,
                                                     float* __restrict__ tr0) {
    int m = blockIdx.y, i = blockIdx.x, j = threadIdx.x;
    const float* mu = means + m * DD;
    const float* g = Gt + (long)m * MSZ;
    int ii = i, jj = j;
    if ((ii >> 7) > (jj >> 7)) { int tmp = ii; ii = jj; jj = tmp; }
    float v = g[(long)ii * DD + jj];
    float val = (v - (float)NROWS * mu[i] * mu[j]) * (1.f / (float)(NROWS - 1));
    C[(long)m * MSZ + (long)i * DD + j] = val;
    if (m == 0 && i == j) atomicAdd(tr0, val);
}

// ---------------- persistent mega-kernel machinery ----------------

// grid barrier: monotonic counter, device scope; all 256 blocks must call uniformly
__device__ __forceinline__ void gbar(unsigned int* cnt, unsigned int& epoch) {
    __syncthreads();
    ++epoch;
    if (threadIdx.x == 0) {
        __threadfence();   // release: make this block's writes visible device-wide
        __hip_atomic_fetch_add(cnt, 1u, __ATOMIC_ACQ_REL, __HIP_MEMORY_SCOPE_AGENT);
        unsigned int target = epoch << 8;          // 256 * epoch
        while (__hip_atomic_load(cnt, __ATOMIC_RELAXED, __HIP_MEMORY_SCOPE_AGENT) < target)
            __builtin_amdgcn_s_sleep(2);
        __threadfence();   // acquire: invalidate stale cached data
    }
    __syncthreads();
}

// operand loads with optional transforms: 0 = plain, 1 = 0.5*(V + V^T), 2 = 0.5*(q1*B + q2*B2)
template<int OP>
__device__ __forceinline__ float4 ldA(const float* __restrict__ A, int r, int c) {
    float4 v = *(const float4*)(A + (long)r * DD + c);
    if (OP == 1) {
        v.x = 0.5f * (v.x + A[(long)(c + 0) * DD + r]);
        v.y = 0.5f * (v.y + A[(long)(c + 1) * DD + r]);
        v.z = 0.5f * (v.z + A[(long)(c + 2) * DD + r]);
        v.w = 0.5f * (v.w + A[(long)(c + 3) * DD + r]);
    }
    return v;
}
template<int OP>
__device__ __forceinline__ float4 ldB(const float* __restrict__ B, const float* __restrict__ B2,
                                      float q1, float q2, int r, int c) {
    float4 v = *(const float4*)(B + (long)r * DD + c);
    if (OP == 1) {
        v.x = 0.5f * (v.x + B[(long)(c + 0) * DD + r]);
        v.y = 0.5f * (v.y + B[(long)(c + 1) * DD + r]);
        v.z = 0.5f * (v.z + B[(long)(c + 2) * DD + r]);
        v.w = 0.5f * (v.w + B[(long)(c + 3) * DD + r]);
    } else if (OP == 2) {
        float4 w = *(const float4*)(B2 + (long)r * DD + c);
        v.x = 0.5f * (q1 * v.x + q2 * w.x);
        v.y = 0.5f * (q1 * v.y + q2 * w.y);
        v.z = 0.5f * (q1 * v.z + q2 * w.z);
        v.w = 0.5f * (q1 * v.w + q2 * w.w);
    }
    return v;
}

// one batched 512x512 gemm stage: 256 blocks = nb matrices x 16 tiles x (16/nb) k-slices.
// Writes raw partial products to pool slices [0..16).
template<int AOP, int BOP>
__device__ __forceinline__ void gemm_stage(const float* __restrict__ Ab0, long long sA,
                                           const float* __restrict__ Bb0, long long sB,
                                           const float* __restrict__ B2, float q1, float q2,
                                           float* __restrict__ pool, int nb, float* lds) {
    float (*As)[132] = (float (*)[132])lds;
    float (*Bs)[140] = (float (*)[140])(lds + 32 * 132);
    int ks = 16 / nb;
    int per = ks << 4;                 // blocks per matrix
    int bid = blockIdx.x;
    int b = bid / per;
    int rem = bid - b * per;
    int s = rem >> 4;
    int tile = rem & 15;
    int i0 = (tile >> 2) << 7;
    int j0 = (tile & 3) << 7;
    int Ks = DD / ks;                  // 32*nb
    int kbase = s * Ks;
    const float* A = Ab0 + (long long)b * sA;
    const float* B = Bb0 + (long long)b * sB;
    int t = threadIdx.x;
    int iy = t >> 4, ix = t & 15;
    int ldr = t >> 3;
    int ldc = (t & 7) << 2;
    int boff = (ix << 3) + ((ix >> 2) << 2);
    float acc[8][8] = {};
    float4 pa[4], pb[4];
    #pragma unroll
    for (int p = 0; p < 4; ++p) {
        pa[p] = ldA<AOP>(A, i0 + ldr + p * 32, kbase + ldc);
        pb[p] = ldB<BOP>(B, B2, q1, q2, kbase + ldr, j0 + ldc + p * 32);
    }
    for (int kb = 0; kb < Ks; kb += 32) {
        __syncthreads();
        #pragma unroll
        for (int p = 0; p < 4; ++p) {
            int r = ldr + p * 32;
            As[ldc + 0][r] = pa[p].x; As[ldc + 1][r] = pa[p].y;
            As[ldc + 2][r] = pa[p].z; As[ldc + 3][r] = pa[p].w;
            int q = (ldc + p * 32) >> 2;
            *(float4*)&Bs[ldr][(q << 2) + ((q >> 3) << 2)] = pb[p];
        }
        __syncthreads();
        if (kb + 32 < Ks) {
            int k0 = kbase + kb + 32;
            #pragma unroll
            for (int p = 0; p < 4; ++p) {
                pa[p] = ldA<AOP>(A, i0 + ldr + p * 32, k0 + ldc);
                pb[p] = ldB<BOP>(B, B2, q1, q2, k0 + ldr, j0 + ldc + p * 32);
            }
        }
        #pragma unroll 4
        for (int kk = 0; kk < 32; ++kk) {
            float a[8], bf[8];
            *(float4*)&a[0] = *(const float4*)&As[kk][iy << 3];
            *(float4*)&a[4] = *(const float4*)&As[kk][(iy << 3) + 4];
            *(float4*)&bf[0] = *(const float4*)&Bs[kk][boff];
            *(float4*)&bf[4] = *(const float4*)&Bs[kk][boff + 4];
            #pragma unroll
            for (int i = 0; i < 8; ++i)
                #pragma unroll
                for (int j = 0; j < 8; ++j)
                    acc[i][j] += a[i] * bf[j];
        }
    }
    float* P = pool + (long long)(b * ks + s) * MSZ;
    #pragma unroll
    for (int i = 0; i < 8; ++i) {
        long off = (long)(i0 + (iy << 3) + i) * DD + j0 + (ix << 3);
        *(float4*)(P + off) = *(float4*)&acc[i][0];
        *(float4*)(P + off + 4) = *(float4*)&acc[i][4];
    }
}

// C_sel(r) = alpha*sum_s pool[r*ks+s] + beta*D_sel(r); optional diag-trace atomicAdd per matrix
__device__ __forceinline__ void reduce_stage(const float* __restrict__ pool, int nb,
                                             const float* D, long long sD, int dsplit, int dskip,
                                             float* C, long long sC, int csplit, int cskip,
                                             float alpha, float beta, float* trslots) {
    int ks = 16 / nb;
    long idx = (((long)blockIdx.x << 8) + threadIdx.x) << 2;
    int row = (int)(idx >> 9);
    int col = (int)(idx & 511);
    #pragma unroll 1
    for (int r = 0; r < nb; ++r) {
        const float* P = pool + (long long)(r * ks) * MSZ + idx;
        float4 a = *(const float4*)P;
        for (int k = 1; k < ks; ++k) {
            float4 v = *(const float4*)(P + (long long)k * MSZ);
            a.x += v.x; a.y += v.y; a.z += v.z; a.w += v.w;
        }
        a.x *= alpha; a.y *= alpha; a.z *= alpha; a.w *= alpha;
        if (beta != 0.f) {
            const float* Db = D + (long long)((r < dsplit) ? r : r + dskip) * sD;
            float4 d = *(const float4*)(Db + idx);
            a.x += beta * d.x; a.y += beta * d.y;
            a.z += beta * d.z; a.w += beta * d.w;
        }
        float* Cb = C + (long long)((r < csplit) ? r : r + cskip) * sC;
        *(float4*)(Cb + idx) = a;
        if (trslots) {
            int dq = row - col;
            if (dq >= 0 && dq < 4) atomicAdd(&trslots[r], (&a.x)[dq]);
        }
    }
}

// fused NS iteration-1: from pool = A@A (raw) produce
//   Y1 = 1.5*invc*A - 0.5*invc^2*pool ; Z1 = 1.5*I - 0.5*invc*A   (invc from trace slot)
__device__ __forceinline__ void nsinit_reduce(const float* __restrict__ pool,
                                              const float* __restrict__ A, long long sAm,
                                              int symA, int nb, float* Y, float* Z,
                                              const float* trb, int trstride) {
    int ks = 16 / nb;
    long idx = (((long)blockIdx.x << 8) + threadIdx.x) << 2;
    int row = (int)(idx >> 9);
    int col = (int)(idx & 511);
    #pragma unroll 1
    for (int r = 0; r < nb; ++r) {
        float c = (2.5f / 512.f) * trb[r * trstride];
        float ic = 1.f / c;
        const float* Ab = A + (long long)r * sAm;
        float4 a = *(const float4*)(Ab + idx);
        if (symA) {
            a.x = 0.5f * (a.x + Ab[(long)(col + 0) * DD + row]);
            a.y = 0.5f * (a.y + Ab[(long)(col + 1) * DD + row]);
            a.z = 0.5f * (a.z + Ab[(long)(col + 2) * DD + row]);
            a.w = 0.5f * (a.w + Ab[(long)(col + 3) * DD + row]);
        }
        const float* P = pool + (long long)(r * ks) * MSZ + idx;
        float4 p = *(const float4*)P;
        for (int k = 1; k < ks; ++k) {
            float4 v = *(const float4*)(P + (long long)k * MSZ);
            p.x += v.x; p.y += v.y; p.z += v.z; p.w += v.w;
        }
        float f15 = 1.5f * ic, f05 = -0.5f * ic * ic, nh = -0.5f * ic;
        float4 y;
        y.x = f15 * a.x + f05 * p.x; y.y = f15 * a.y + f05 * p.y;
        y.z = f15 * a.z + f05 * p.z; y.w = f15 * a.w + f05 * p.w;
        *(float4*)(Y + (long long)r * MSZ + idx) = y;
        float4 z;
        z.x = nh * a.x; z.y = nh * a.y; z.z = nh * a.z; z.w = nh * a.w;
        int dq = row - col;
        if (dq >= 0 && dq < 4) (&z.x)[dq] += 1.5f;
        *(float4*)(Z + (long long)r * MSZ + idx) = z;
    }
}

// NS tail iterations 2..7 on nb matrices, layout [Y | W | Z] each nb*MSZ
__device__ __forceinline__ void ns_tail(float* Y, float* W, int nb, float* pool,
                                        unsigned int* cnt, unsigned int& ep, float* lds) {
    #pragma unroll 1
    for (int it = 1; it < NS_ITERS; ++it) {
        gemm_stage<0, 0>(Y + 2ll * nb * MSZ, MSZ, Y, MSZ, nullptr, 0.f, 0.f, pool, nb, lds); // W=Z@Y
        gbar(cnt, ep);
        reduce_stage(pool, nb, nullptr, 0, nb, 0, W, MSZ, nb, 0, 1.f, 0.f, nullptr);
        gbar(cnt, ep);
        gemm_stage<0, 0>(Y, MSZ, W, MSZ, nullptr, 0.f, 0.f, pool, 2 * nb, lds);  // [Y@W.., W@Z..]
        gbar(cnt, ep);
        reduce_stage(pool, 2 * nb, Y, MSZ, nb, nb, Y, MSZ, nb, nb, -0.5f, 1.5f, nullptr);
        gbar(cnt, ep);
    }
}

__device__ __forceinline__ void bias_dev(const float* __restrict__ M, const float* __restrict__ ws,
                                         float* __restrict__ bias, float* lds) {
    #pragma unroll 1
    for (int rr = 0; rr < 2; ++rr) {
        int r = (blockIdx.x << 1) + rr;
        int t = threadIdx.x;
        float p = ws[t] * M[(long)r * DD + t] + ws[t + 256] * M[(long)r * DD + t + 256];
        lds[t] = p;
        __syncthreads();
        for (int s2 = 128; s2 > 0; s2 >>= 1) {
            if (t < s2) lds[t] += lds[t + s2];
            __syncthreads();
        }
        if (t == 0) bias[r] = ws[1024 + r] - lds[0];
        __syncthreads();
    }
}

// ---------------- the persistent mega-kernel ----------------
__global__ __launch_bounds__(256) void mega_kernel(float* __restrict__ ws, float* __restrict__ pool) {
    __shared__ float lds[32 * 272];
    float* MATS = ws + 4096;
    float* covc = MATS;                       // m0 (m1 = covs)
    float* Y    = MATS + 3ll * MSZ;           // m3
    float* W    = MATS + 4ll * MSZ;           // m4 (also U)
    float* Z    = MATS + 5ll * MSZ;           // m5
    float* Mx   = MATS + 6ll * MSZ;           // m6 final M
    float* mid  = MATS + 7ll * MSZ;           // m7,m8 (m7 also V)
    float* blk  = MATS + 9ll * MSZ;           // m9..m14: [Yb0,Yb1,Wb0,Wb1,Zb0,Zb1]
    unsigned int* cnt = (unsigned int*)(ws + 2048);
    float* trSig  = ws + 2064;                // [0..16], [0]=tr(covc) from covfix
    float* trMid  = ws + 2112;                // 32 slots
    float* trMidF = ws + 2152;                // 1 slot
    unsigned int ep = 0;
    const float* Sig = covc;

    #pragma unroll 1
    for (int iter = 0; iter < BARY_ITERS; ++iter) {
        const float* trS = trSig + iter;
        // ---- NS on sym(Sig): iter-1 fused ----
        gemm_stage<1, 1>(Sig, 0, Sig, 0, nullptr, 0.f, 0.f, pool, 1, lds);
        gbar(cnt, ep);
        nsinit_reduce(pool, Sig, 0, 1, 1, Y, Z, trS, 0);
        gbar(cnt, ep);
        ns_tail(Y, W, 1, pool, cnt, ep, lds);
        // ---- P_j = Y @ cov_j (nb=2, A stride 0) -> m9,m10 ----
        gemm_stage<0, 0>(Y, 0, covc, MSZ, nullptr, 0.f, 0.f, pool, 2, lds);
        gbar(cnt, ep);
        reduce_stage(pool, 2, nullptr, 0, 2, 0, blk, MSZ, 2, 0, 1.f, 0.f, nullptr);
        gbar(cnt, ep);
        // ---- mid_j = c0 * P_j @ Y -> m7,m8 (+ traces) ----
        float c0 = (2.5f / 512.f) * trS[0];
        gemm_stage<0, 0>(blk, MSZ, Y, 0, nullptr, 0.f, 0.f, pool, 2, lds);
        gbar(cnt, ep);
        reduce_stage(pool, 2, nullptr, 0, 2, 0, mid, MSZ, 2, 0, c0, 0.f, trMid + 2 * iter);
        gbar(cnt, ep);
        // ---- NS on mid (nb=2) in blk ----
        gemm_stage<0, 0>(mid, MSZ, mid, MSZ, nullptr, 0.f, 0.f, pool, 2, lds);
        gbar(cnt, ep);
        nsinit_reduce(pool, mid, MSZ, 0, 2, blk, blk + 4ll * MSZ, trMid + 2 * iter, 1);
        gbar(cnt, ep);
        ns_tail(blk, blk + 2ll * MSZ, 2, pool, cnt, ep, lds);
        // ---- U = Z @ Q, Q = 0.5*(sqrt(c1)*Yb0 + sqrt(c2)*Yb1) fused -> m4 ----
        float c1 = (2.5f / 512.f) * trMid[2 * iter];
        float c2 = (2.5f / 512.f) * trMid[2 * iter + 1];
        gemm_stage<0, 2>(Z, 0, blk, 0, blk + MSZ, sqrtf(c1), sqrtf(c2), pool, 1, lds);
        gbar(cnt, ep);
        reduce_stage(pool, 1, nullptr, 0, 1, 0, W, 0, 1, 0, 1.f, 0.f, nullptr);
        gbar(cnt, ep);
        // ---- V = (1/c0)*U@Z -> m7 (+ trace for next iter's Sigma) ----
        gemm_stage<0, 0>(W, 0, Z, 0, nullptr, 0.f, 0.f, pool, 1, lds);
        gbar(cnt, ep);
        reduce_stage(pool, 1, nullptr, 0, 1, 0, mid, 0, 1, 0, 1.f / c0, 0.f, trSig + iter + 1);
        gbar(cnt, ep);
        Sig = mid;   // Sigma_{t+1} = sym(V), applied on load
    }

    // ======== final transform: M = covc^{-1/2} (covc^{1/2} Sigma covc^{1/2})^{1/2} covc^{-1/2} ====
    gemm_stage<1, 1>(covc, 0, covc, 0, nullptr, 0.f, 0.f, pool, 1, lds);
    gbar(cnt, ep);
    nsinit_reduce(pool, covc, 0, 1, 1, Y, Z, trSig, 0);
    gbar(cnt, ep);
    ns_tail(Y, W, 1, pool, cnt, ep, lds);
    float c0f = (2.5f / 512.f) * trSig[0];
    // P = Y @ sym(V) -> m9
    gemm_stage<0, 1>(Y, 0, Sig, 0, nullptr, 0.f, 0.f, pool, 1, lds);
    gbar(cnt, ep);
    reduce_stage(pool, 1, nullptr, 0, 1, 0, blk, 0, 1, 0, 1.f, 0.f, nullptr);
    gbar(cnt, ep);
    // midF = c0f * P @ Y -> m7 (+ trace)
    gemm_stage<0, 0>(blk, 0, Y, 0, nullptr, 0.f, 0.f, pool, 1, lds);
    gbar(cnt, ep);
    reduce_stage(pool, 1, nullptr, 0, 1, 0, mid, 0, 1, 0, c0f, 0.f, trMidF);
    gbar(cnt, ep);
    // NS on midF (nb=1) in blk: Yb=m9, Wf=m10, Zf=m11
    gemm_stage<0, 0>(mid, 0, mid, 0, nullptr, 0.f, 0.f, pool, 1, lds);
    gbar(cnt, ep);
    nsinit_reduce(pool, mid, 0, 0, 1, blk, blk + 2ll * MSZ, trMidF, 0);
    gbar(cnt, ep);
    ns_tail(blk, blk + MSZ, 1, pool, cnt, ep, lds);
    float c1f = (2.5f / 512.f) * trMidF[0];
    // U' = sqrt(c1f)*Z@Yb -> m4
    gemm_stage<0, 0>(Z, 0, blk, 0, nullptr, 0.f, 0.f, pool, 1, lds);
    gbar(cnt, ep);
    reduce_stage(pool, 1, nullptr, 0, 1, 0, W, 0, 1, 0, sqrtf(c1f), 0.f, nullptr);
    gbar(cnt, ep);
    // M = (1/c0f)*U'@Z -> m6
    gemm_stage<0, 0>(W, 0, Z, 0, nullptr, 0.f, 0.f, pool, 1, lds);
    gbar(cnt, ep);
    reduce_stage(pool, 1, nullptr, 0, 1, 0, Mx, 0, 1, 0, 1.f / c0f, 0.f, nullptr);
    gbar(cnt, ep);
    // bias_j = mu_b[j] - sum_k mu_c[k]*M[j][k]
    bias_dev(Mx, ws, ws + 1536, lds);
}

// out = X @ M^T + bias; 128x128 tiles, 8x8 micro. grid (4 j-tiles, 512 i-tiles).
__global__ __launch_bounds__(256) void outgemm2_kernel(const float* __restrict__ X,
                                                       const float* __restrict__ M,
                                                       const float* __restrict__ bias,
                                                       float* __restrict__ out) {
    int j0 = blockIdx.x << 7;
    int i0 = blockIdx.y << 7;
    __shared__ float As[32][132];   // As[k][i]
    __shared__ float Bs[32][140];   // Bs[k][j], quad-swizzled j
    int t = threadIdx.x;
    int iy = t >> 4, ix = t & 15;
    int ldr = t >> 3;               // 0..31
    int ldc = (t & 7) << 2;         // 0..28 (k within 32-block)
    int boff = (ix << 3) + ((ix >> 2) << 2);
    float acc[8][8] = {};
    float4 pa[4], pb[4];
    #pragma unroll
    for (int p = 0; p < 4; ++p) {
        pa[p] = *(const float4*)(X + (long)(i0 + ldr + p * 32) * DD + ldc);
        pb[p] = *(const float4*)(M + (long)(j0 + ldr + p * 32) * DD + ldc);
    }
    for (int kb = 0; kb < DD; kb += 32) {
        __syncthreads();
        #pragma unroll
        for (int p = 0; p < 4; ++p) {
            int r = ldr + p * 32;
            As[ldc + 0][r] = pa[p].x; As[ldc + 1][r] = pa[p].y;
            As[ldc + 2][r] = pa[p].z; As[ldc + 3][r] = pa[p].w;
            int q = r >> 2;
            int bc = (q << 2) + ((q >> 3) << 2) + (r & 3);
            Bs[ldc + 0][bc] = pb[p].x; Bs[ldc + 1][bc] = pb[p].y;
            Bs[ldc + 2][bc] = pb[p].z; Bs[ldc + 3][bc] = pb[p].w;
        }
        __syncthreads();
        if (kb + 32 < DD) {
            #pragma unroll
            for (int p = 0; p < 4; ++p) {
                pa[p] = *(const float4*)(X + (long)(i0 + ldr + p * 32) * DD + kb + 32 + ldc);
                pb[p] = *(const float4*)(M + (long)(j0 + ldr + p * 32) * DD + kb + 32 + ldc);
            }
        }
        #pragma unroll 4
        for (int kk = 0; kk < 32; ++kk) {
            float a[8], bf[8];
            *(float4*)&a[0] = *(const float4*)&As[kk][iy << 3];
            *(float4*)&a[4] = *(const float4*)&As[kk][(iy << 3) + 4];
            *(float4*)&bf[0] = *(const float4*)&Bs[kk][boff];
            *(float4*)&bf[4] = *(const float4*)&Bs[kk][boff + 4];
            #pragma unroll
            for (int i = 0; i < 8; ++i)
                #pragma unroll
                for (int j = 0; j < 8; ++j)
                    acc[i][j] += a[i] * bf[j];
        }
    }
    float4 bv0 = *(const float4*)(bias + j0 + (ix << 3));
    float4 bv1 = *(const float4*)(bias + j0 + (ix << 3) + 4);
    #pragma unroll
    for (int i = 0; i < 8; ++i) {
        long off = (long)(i0 + (iy << 3) + i) * DD + j0 + (ix << 3);
        float4 v0 = *(float4*)&acc[i][0];
        float4 v1 = *(float4*)&acc[i][4];
        v0.x += bv0.x; v0.y += bv0.y; v0.z += bv0.z; v0.w += bv0.w;
        v1.x += bv1.x; v1.y += bv1.y; v1.z += bv1.z; v1.w += bv1.w;
        *(float4*)(out + off) = v0;
        *(float4*)(out + off + 4) = v1;
    }
}

// ---------------- host orchestration ----------------
extern "C" void kernel_launch(void* const* d_in, const int* in_sizes, int n_in,
                              void* d_out, int out_size, void* d_ws, size_t ws_size,
                              hipStream_t stream) {
    const float* X = (const float*)d_in[0];
    const float* S = (const float*)d_in[1];
    float* out = (float*)d_out;
    float* ws = (float*)d_ws;
    float* pool = out;   // 16 MB partial pool lives in d_out (134 MB); dead until final outgemm

    // ws layout (floats):
    // [0,512)=mean_c [512,1024)=mean_s [1024,1536)=mu_b [1536,2048)=bias
    // 2048=barrier cnt, 2064..2080=trSig, 2112..2143=trMid, 2152=trMidF
    // MATS = ws+4096 (15 matrices, ~15 MB): m0 covc, m1 covs, m3 Y, m4 W/U, m5 Z,
    //   m6 M, m7 mid0/V, m8 mid1, m9..m14 batch blk
    float* MATS = ws + 4096;
    float* covc = MATS;
    float* Mx   = MATS + 6ll * MSZ;

    hipMemsetAsync(ws, 0, 4096 * sizeof(float), stream);             // means + slots + barrier
    hipMemsetAsync(pool, 0, 2ll * MSZ * sizeof(float), stream);      // covsyrk accumulators

    colsum_kernel<<<dim3(256, 2), 512, 0, stream>>>(X, S, ws);
    finalize_mean_kernel<<<1, 512, 0, stream>>>(ws);
    covsyrk2_kernel<<<dim3(16, CSPLIT, 2), 256, 0, stream>>>(X, S, pool);
    covfix_kernel<<<dim3(512, 2), 512, 0, stream>>>(pool, covc, ws, ws + 2064);
    mega_kernel<<<dim3(256), 256, 0, stream>>>(ws, pool);
    outgemm2_kernel<<<dim3(4, 512), 256, 0, stream>>>(X, Mx, ws + 1536, out);
}